// Round 5
// baseline (4086.299 us; speedup 1.0000x reference)
//
#include <hip/hip_runtime.h>
#include <hip/hip_bf16.h>
#include <cstdint>

#define DEV __device__ __forceinline__

// Problem constants (from setup_inputs)
constexpr int Bn   = 8;
constexpr int Nn   = 4096;
constexpr int Mn   = 1024;   // N / STRIDE
constexpr int Kn   = 32;     // NSAMPLE
constexpr int CIN  = 64;
constexpr int COUT = 128;

// ---------------------------------------------------------------------------
// feats (B, 64, 4096) -> featsT (B, 4096, 64)
// ---------------------------------------------------------------------------
__global__ __launch_bounds__(256) void k_tr(const float* __restrict__ feats,
                                            float* __restrict__ featsT) {
  __shared__ float tile[64][65];
  int b = blockIdx.x >> 6, n0 = (blockIdx.x & 63) * 64;
  int t = threadIdx.x;
  int lane = t & 63, grp = t >> 6;
  for (int r = 0; r < 16; ++r) {
    int c = grp + r * 4;
    tile[c][lane] = feats[((size_t)b * 64 + c) * 4096 + n0 + lane];
  }
  __syncthreads();
  for (int r = 0; r < 16; ++r) {
    int n = grp + r * 4;
    featsT[((size_t)b * 4096 + n0 + n) * 64 + lane] = tile[lane][n];
  }
}

// ---------------------------------------------------------------------------
// FPS v3: cooperative multi-CU. 8 batches x 16 blocks x 256 threads
// (1 point per thread, 64 waves per batch). Per iteration each wave:
// update md -> DPP wave-max -> publish u64 self-tagged key to global mailbox
// (device-scope atomic) -> spin-load all 64 wave slots -> DPP merge ->
// readlane broadcast. No __syncthreads in the loop; waves fully independent.
// Decision arithmetic bit-identical to numpy ref (no FMA contraction,
// first-index tie-break): key = valbits<<23 | (4095-idx)<<11 | iter_tag(11b).
// batch = blockIdx&7 so mailbox traffic stays XCD-local if bid%8 == XCD.
// ---------------------------------------------------------------------------
DEV unsigned long long wave_max_key(unsigned long long key) {
#if __has_builtin(__builtin_amdgcn_update_dpp)
#define DPP_STEP(CTRL, RMASK)                                                          \
  {                                                                                    \
    unsigned int lo2 = (unsigned int)__builtin_amdgcn_update_dpp(                      \
        0, (int)(unsigned int)key, CTRL, RMASK, 0xf, false);                           \
    unsigned int hi2 = (unsigned int)__builtin_amdgcn_update_dpp(                      \
        0, (int)(unsigned int)(key >> 32), CTRL, RMASK, 0xf, false);                   \
    unsigned long long k2 = ((unsigned long long)hi2 << 32) | lo2;                     \
    if (k2 > key) key = k2;                                                            \
  }
  DPP_STEP(0x111, 0xf)  // row_shr:1
  DPP_STEP(0x112, 0xf)  // row_shr:2
  DPP_STEP(0x114, 0xf)  // row_shr:4
  DPP_STEP(0x118, 0xf)  // row_shr:8
  DPP_STEP(0x142, 0xa)  // row_bcast:15 rows 1,3
  DPP_STEP(0x143, 0xc)  // row_bcast:31 rows 2,3
#undef DPP_STEP
#else
  for (int off = 1; off < 64; off <<= 1) {
    unsigned int lo2 = __shfl_xor((unsigned int)key, off, 64);
    unsigned int hi2 = __shfl_xor((unsigned int)(key >> 32), off, 64);
    unsigned long long k2 = ((unsigned long long)hi2 << 32) | lo2;
    if (k2 > key) key = k2;
  }
#endif
  return key;  // lane 63 holds the wave max
}

__global__ __launch_bounds__(256, 2) void k_fps(const float* __restrict__ coords,
                                                uint32_t* __restrict__ sidx,
                                                float* __restrict__ outc,
                                                unsigned long long* __restrict__ gpart) {
  const int bid = blockIdx.x;
  const int b   = bid & 7;    // batch (XCD-aligned if round-robin mapping)
  const int blk = bid >> 3;   // block-in-batch 0..15
  const int t   = threadIdx.x;
  __shared__ float4 sp[Nn];        // full coord copy, 64 KB
  __shared__ uint32_t farl[Mn];    // used by blk 0 only
  __shared__ float s_mean[4];

  const float* cb = coords + (size_t)b * Nn * 3;
  for (int i = t; i < Nn; i += 256)
    sp[i] = make_float4(cb[3 * i], cb[3 * i + 1], cb[3 * i + 2], 0.f);
  __syncthreads();
  if (t == 0) {  // sequential in-order fp32 mean (matches ref; passed R1-R4)
    float ax = 0.f, ay = 0.f, az = 0.f;
    for (int i = 0; i < Nn; ++i) {
      float4 c = sp[i];
      ax = __fadd_rn(ax, c.x); ay = __fadd_rn(ay, c.y); az = __fadd_rn(az, c.z);
    }
    s_mean[0] = __fdiv_rn(ax, 4096.f);
    s_mean[1] = __fdiv_rn(ay, 4096.f);
    s_mean[2] = __fdiv_rn(az, 4096.f);
  }
  __syncthreads();

  const int myidx = blk * 256 + t;          // this thread's point
  float4 mp = sp[myidx];
  const float px = mp.x, py = mp.y, pz = mp.z;
  float md = __builtin_inff();
  const unsigned long long invb = (unsigned long long)(4095u - (uint32_t)myidx) << 11;
  const int w = blk * 4 + (t >> 6);         // wave id within batch, 0..63
  unsigned long long* gp = gpart + (size_t)b * 128;  // 64 waves x 2 slots

  uint32_t far;
#define FPS_ROUND(TV, P)                                                               \
  {                                                                                    \
    unsigned long long key =                                                           \
        ((unsigned long long)__float_as_uint(TV) << 23) | invb;                        \
    key = wave_max_key(key);                                                           \
    const int sl = (P) & 1;                                                            \
    if ((t & 63) == 63)                                                                \
      __hip_atomic_store(&gp[w * 2 + sl], key | (unsigned long long)(P),               \
                         __ATOMIC_RELAXED, __HIP_MEMORY_SCOPE_AGENT);                  \
    unsigned long long kk;                                                             \
    int g = 0;                                                                         \
    bool ok;                                                                           \
    do {                                                                               \
      kk = __hip_atomic_load(&gp[(t & 63) * 2 + sl], __ATOMIC_RELAXED,                 \
                             __HIP_MEMORY_SCOPE_AGENT);                                \
      ok = (((unsigned int)kk ^ (unsigned int)(P)) & 2047u) == 0u;                     \
    } while (!__all(ok) && ++g < (1 << 22));                                           \
    kk = wave_max_key(kk);                                                             \
    unsigned int lo = (unsigned int)__builtin_amdgcn_readlane((int)(unsigned int)kk, 63); \
    far = 4095u - ((lo >> 11) & 4095u);                                                \
  }

  {
    float mx = s_mean[0], my = s_mean[1], mz = s_mean[2];
    float dx = __fsub_rn(px, mx), dy = __fsub_rn(py, my), dz = __fsub_rn(pz, mz);
    float tv = __fadd_rn(__fadd_rn(__fmul_rn(dx, dx), __fmul_rn(dy, dy)), __fmul_rn(dz, dz));
    FPS_ROUND(tv, 0)
  }
  for (int p = 1; p < Mn; ++p) {
    if (blk == 0 && t == 0) farl[p - 1] = far;
    float4 c = sp[far];
    float dx = __fsub_rn(px, c.x), dy = __fsub_rn(py, c.y), dz = __fsub_rn(pz, c.z);
    float d = __fadd_rn(__fadd_rn(__fmul_rn(dx, dx), __fmul_rn(dy, dy)), __fmul_rn(dz, dz));
    md = fminf(md, d);
    FPS_ROUND(md, p)
  }
#undef FPS_ROUND

  if (blk == 0) {
    if (t == 0) farl[Mn - 1] = far;
    __syncthreads();
    for (int i = t; i < Mn; i += 256) {
      uint32_t f = farl[i];
      sidx[b * Mn + i] = f;
      float4 c = sp[f];
      outc[(size_t)(b * Mn + i) * 3 + 0] = c.x;
      outc[(size_t)(b * Mn + i) * 3 + 1] = c.y;
      outc[(size_t)(b * Mn + i) * 3 + 2] = c.z;
    }
  }
}

// ---------------------------------------------------------------------------
// 32-NN per query (== reference ball_query+knn fallback) + density weights.
// Compact within-radius candidates, rank-select 32 smallest (d2,idx) keys.
// Radius expansion 0.04 -> 0.16 -> inf if fewer than 32 candidates.
// ---------------------------------------------------------------------------
__global__ __launch_bounds__(256) void k_knn(const float* __restrict__ coords,
                                             const uint32_t* __restrict__ sidx,
                                             uint32_t* __restrict__ gidx,
                                             float* __restrict__ wts) {
  const int q = blockIdx.x;
  const int b = q >> 10;
  const int t = threadIdx.x;
  __shared__ unsigned long long keys[Nn + 2];
  __shared__ int s_cnt;
  __shared__ float s_q[4];
  __shared__ uint32_t s_sel[32];
  __shared__ float gx[32], gy[32], gz[32], g2[32];
  __shared__ float dmat[32 * 33];
  __shared__ float kth[32];
  __shared__ float s_raw[32];
  __shared__ float s_sum;

  if (t == 0) {
    uint32_t si = sidx[q];
    const float* c = &coords[((size_t)b * Nn + si) * 3];
    s_q[0] = c[0]; s_q[1] = c[1]; s_q[2] = c[2];
  }
  __syncthreads();
  float qx = s_q[0], qy = s_q[1], qz = s_q[2];
  float q2 = __fadd_rn(__fadd_rn(__fmul_rn(qx, qx), __fmul_rn(qy, qy)), __fmul_rn(qz, qz));
  const float* cb = coords + (size_t)b * Nn * 3;

  float thr = 0.04f;
  int cnt = 0;
  while (true) {
    if (t == 0) s_cnt = 0;
    __syncthreads();
    for (int j = 0; j < 16; ++j) {
      int i = t + 256 * j;
      float cx = cb[3 * i], cy = cb[3 * i + 1], cz = cb[3 * i + 2];
      float c2  = __fadd_rn(__fadd_rn(__fmul_rn(cx, cx), __fmul_rn(cy, cy)), __fmul_rn(cz, cz));
      float dot = __fadd_rn(__fadd_rn(__fmul_rn(qx, cx), __fmul_rn(qy, cy)), __fmul_rn(qz, cz));
      float d2  = __fsub_rn(__fadd_rn(q2, c2), __fmul_rn(2.f, dot));
      float d2c = fmaxf(d2, 1e-12f);
      bool pred = (d2c <= thr);
      unsigned long long mk = __ballot(pred);
      int base = 0;
      if ((t & 63) == 0 && mk) base = atomicAdd(&s_cnt, (int)__popcll(mk));
      base = __shfl(base, 0, 64);
      if (pred) {
        int pos = base + (int)__popcll(mk & ((1ull << (t & 63)) - 1ull));
        keys[pos] = ((unsigned long long)__float_as_uint(d2c) << 32) | (uint32_t)i;
      }
    }
    __syncthreads();
    cnt = s_cnt;
    if (cnt >= 32 || thr > 1.f) break;
    thr = (thr < 0.1f) ? 0.16f : 8.f;
    __syncthreads();
  }
  if (t == 0) { keys[cnt] = ~0ull; keys[cnt + 1] = ~0ull; }
  __syncthreads();
  int cnt2 = (cnt + 1) & ~1;
  for (int i = t; i < cnt; i += 256) {
    unsigned long long ki = keys[i];
    int r = 0;
    for (int j2 = 0; j2 < cnt2; j2 += 2) {
      unsigned long long a = keys[j2], c2 = keys[j2 + 1];
      r += (a < ki) + (c2 < ki);
    }
    if (r < 32) s_sel[r] = (uint32_t)ki;
  }
  __syncthreads();

  if (t < 32) {
    uint32_t gi = s_sel[t];
    gidx[(size_t)q * 32 + t] = gi;
    const float* c = &coords[((size_t)b * Nn + gi) * 3];
    float x = c[0], y = c[1], z = c[2];
    gx[t] = x; gy[t] = y; gz[t] = z;
    g2[t] = __fadd_rn(__fadd_rn(__fmul_rn(x, x), __fmul_rn(y, y)), __fmul_rn(z, z));
  }
  __syncthreads();
  for (int p = t; p < 1024; p += 256) {
    int i = p >> 5, jj = p & 31;
    float dot = __fadd_rn(__fadd_rn(__fmul_rn(gx[i], gx[jj]), __fmul_rn(gy[i], gy[jj])),
                          __fmul_rn(gz[i], gz[jj]));
    float d2 = __fsub_rn(__fadd_rn(g2[i], g2[jj]), __fmul_rn(2.f, dot));
    float dd = sqrtf(fmaxf(d2, 1e-12f));
    if (i == jj) dd = __builtin_inff();
    dmat[i * 33 + jj] = dd;
  }
  __syncthreads();
  for (int p = t; p < 1024; p += 256) {
    int i = p >> 5, jj = p & 31;
    float v = dmat[i * 33 + jj];
    int r = 0;
    for (int c = 0; c < 32; ++c) {
      float u = dmat[i * 33 + c];
      r += (u < v) || (u == v && c < jj);
    }
    if (r == 15) kth[i] = v;
  }
  __syncthreads();
  if (t < 32) { float x = fmaxf(kth[t], 1e-8f); s_raw[t] = x * x * x; }
  __syncthreads();
  if (t == 0) {
    float s = 0.f;
    for (int i2 = 0; i2 < 32; ++i2) s += s_raw[i2];
    s_sum = fmaxf(s, 1e-8f);
  }
  __syncthreads();
  if (t < 32) wts[(size_t)q * 32 + t] = s_raw[t] / s_sum;
}

// ---------------------------------------------------------------------------
// Conv pipeline. Tile = 4 queries x 32 neighbors (GEMM k-dim = 128).
// Thread tile: 4 outputs x 8 k (o0 = (t&15)*4, k0 = (t>>4)*8).
// LDS: xs[67][132] (row 0..2 = rel, 3..66 = feats), w0sT[67][68] (W0^T).
// ---------------------------------------------------------------------------
constexpr int XST = 132;
constexpr int WST = 68;

DEV void build_x(const float* __restrict__ coords, const float* __restrict__ featsT,
                 const uint32_t* __restrict__ sidx, const uint32_t* __restrict__ gidx,
                 const float* __restrict__ W0, int b, int m0, int t,
                 float* xs, float* w0sT, uint32_t* s_gi, float* s_qc) {
  for (int i = t; i < 64 * 67; i += 256) {
    int o = i / 67, c = i - o * 67;
    w0sT[c * WST + o] = W0[i];
  }
  if (t < 128) {
    s_gi[t] = gidx[((size_t)(b * Mn + m0)) * 32 + t];
  } else if (t < 132) {
    int mm = t - 128;
    uint32_t si = sidx[b * Mn + m0 + mm];
    const float* c = &coords[((size_t)b * Nn + si) * 3];
    s_qc[mm * 3 + 0] = c[0]; s_qc[mm * 3 + 1] = c[1]; s_qc[mm * 3 + 2] = c[2];
  }
  __syncthreads();
  if (t < 128) {
    int mm = t >> 5;
    const float* c = &coords[((size_t)b * Nn + s_gi[t]) * 3];
    xs[0 * XST + t] = (c[0] - s_qc[mm * 3 + 0]) / 0.2f;
    xs[1 * XST + t] = (c[1] - s_qc[mm * 3 + 1]) / 0.2f;
    xs[2 * XST + t] = (c[2] - s_qc[mm * 3 + 2]) / 0.2f;
  }
  {
    int c = t & 63, k0g = t >> 6;
    for (int r2 = 0; r2 < 32; ++r2) {
      int kk = k0g + 4 * r2;
      xs[(size_t)(3 + c) * XST + kk] = featsT[((size_t)b * Nn + s_gi[kk]) * 64 + c];
    }
  }
  __syncthreads();
}

DEV void conv1_acc(const float* xs, const float* w0sT, int o0, int k0, float acc[32]) {
#pragma unroll
  for (int i = 0; i < 32; ++i) acc[i] = 0.f;
  for (int c = 0; c < 67; ++c) {
    float4 w  = *(const float4*)&w0sT[c * WST + o0];
    float4 xa = *(const float4*)&xs[c * XST + k0];
    float4 xb = *(const float4*)&xs[c * XST + k0 + 4];
    float wv[4] = {w.x, w.y, w.z, w.w};
    float xv[8] = {xa.x, xa.y, xa.z, xa.w, xb.x, xb.y, xb.z, xb.w};
#pragma unroll
    for (int i = 0; i < 4; ++i)
#pragma unroll
      for (int j = 0; j < 8; ++j)
        acc[i * 8 + j] = fmaf(wv[i], xv[j], acc[i * 8 + j]);
  }
}

DEV void conv2_acc(const float* hs, const float* w1sT, int o0, int k0, float acc2[32]) {
#pragma unroll
  for (int i = 0; i < 32; ++i) acc2[i] = 0.f;
  for (int c = 0; c < 64; ++c) {
    float4 w  = *(const float4*)&w1sT[c * WST + o0];
    float4 xa = *(const float4*)&hs[c * XST + k0];
    float4 xb = *(const float4*)&hs[c * XST + k0 + 4];
    float wv[4] = {w.x, w.y, w.z, w.w};
    float xv[8] = {xa.x, xa.y, xa.z, xa.w, xb.x, xb.y, xb.z, xb.w};
#pragma unroll
    for (int i = 0; i < 4; ++i)
#pragma unroll
      for (int j = 0; j < 8; ++j)
        acc2[i * 8 + j] = fmaf(wv[i], xv[j], acc2[i * 8 + j]);
  }
}

// stats layout (floats): [0,64) s0 | [64,128) q0 | [128,256) s1 | [256,384) q1
// | [384,512) ss | [512,640) qs | 640 a0 | 704 c0 | 768 a1 | 896 c1
// | 1024 as | 1152 cs
__global__ __launch_bounds__(256) void k_conv1(const float* __restrict__ coords,
                                               const float* __restrict__ featsT,
                                               const uint32_t* __restrict__ sidx,
                                               const uint32_t* __restrict__ gidx,
                                               const float* __restrict__ W0,
                                               float* __restrict__ stats) {
  __shared__ float xs[67 * XST];
  __shared__ float w0sT[67 * WST];
  __shared__ uint32_t s_gi[128];
  __shared__ float s_qc[12];
  __shared__ float ssum[64], ssq[64];
  int blk = blockIdx.x, t = threadIdx.x;
  int b = blk >> 8, m0 = (blk & 255) << 2;
  if (t < 64) { ssum[t] = 0.f; ssq[t] = 0.f; }
  build_x(coords, featsT, sidx, gidx, W0, b, m0, t, xs, w0sT, s_gi, s_qc);
  int o0 = (t & 15) * 4, k0 = (t >> 4) * 8;
  float acc[32];
  conv1_acc(xs, w0sT, o0, k0, acc);
#pragma unroll
  for (int i = 0; i < 4; ++i) {
    float s = 0.f, sq = 0.f;
#pragma unroll
    for (int j = 0; j < 8; ++j) { s += acc[i * 8 + j]; sq = fmaf(acc[i * 8 + j], acc[i * 8 + j], sq); }
    atomicAdd(&ssum[o0 + i], s); atomicAdd(&ssq[o0 + i], sq);
  }
  __syncthreads();
  if (t < 64) { atomicAdd(&stats[t], ssum[t]); atomicAdd(&stats[64 + t], ssq[t]); }
}

__global__ void k_fin0(float* stats, const float* g0, const float* b0) {
  int t = threadIdx.x;
  if (t >= 64) return;
  float mu  = stats[t] * (1.f / 262144.f);
  float var = stats[64 + t] * (1.f / 262144.f) - mu * mu;
  float a = g0[t] / sqrtf(var + 1e-5f);
  stats[640 + t] = a;
  stats[704 + t] = b0[t] - mu * a;
}

__global__ __launch_bounds__(256) void k_conv2(const float* __restrict__ coords,
                                               const float* __restrict__ featsT,
                                               const uint32_t* __restrict__ sidx,
                                               const uint32_t* __restrict__ gidx,
                                               const float* __restrict__ W0,
                                               const float* __restrict__ W1,
                                               float* __restrict__ stats) {
  __shared__ float smU[13400];  // xs+w0sT (8844+4556) | hs+w1sT (8448+4352)
  __shared__ uint32_t s_gi[128];
  __shared__ float s_qc[12];
  __shared__ float ssum[128], ssq[128];
  float* xs = smU;  float* w0sT = smU + 67 * XST;
  float* hs = smU;  float* w1sT = smU + 64 * XST;
  int blk = blockIdx.x, t = threadIdx.x;
  int b = blk >> 8, m0 = (blk & 255) << 2;
  if (t < 128) { ssum[t] = 0.f; ssq[t] = 0.f; }
  build_x(coords, featsT, sidx, gidx, W0, b, m0, t, xs, w0sT, s_gi, s_qc);
  int o0 = (t & 15) * 4, k0 = (t >> 4) * 8;
  float acc[32];
  conv1_acc(xs, w0sT, o0, k0, acc);
  float4 a04 = *(const float4*)&stats[640 + o0];
  float4 c04 = *(const float4*)&stats[704 + o0];
  float a0v[4] = {a04.x, a04.y, a04.z, a04.w};
  float c0v[4] = {c04.x, c04.y, c04.z, c04.w};
  __syncthreads();  // all conv1 LDS reads complete; smU repurposed
#pragma unroll
  for (int i = 0; i < 4; ++i) {
    float h[8];
#pragma unroll
    for (int j = 0; j < 8; ++j) h[j] = fmaxf(fmaf(a0v[i], acc[i * 8 + j], c0v[i]), 0.f);
    *(float4*)&hs[(o0 + i) * XST + k0]     = make_float4(h[0], h[1], h[2], h[3]);
    *(float4*)&hs[(o0 + i) * XST + k0 + 4] = make_float4(h[4], h[5], h[6], h[7]);
  }
  for (int p = 0; p < 2; ++p) {
    __syncthreads();
    for (int i = t; i < 64 * 64; i += 256) {
      int oo = i >> 6, cc = i & 63;
      w1sT[cc * WST + oo] = W1[(size_t)(64 * p + oo) * 64 + cc];
    }
    __syncthreads();
    float acc2[32];
    conv2_acc(hs, w1sT, o0, k0, acc2);
#pragma unroll
    for (int i = 0; i < 4; ++i) {
      float s = 0.f, sq = 0.f;
#pragma unroll
      for (int j = 0; j < 8; ++j) { s += acc2[i * 8 + j]; sq = fmaf(acc2[i * 8 + j], acc2[i * 8 + j], sq); }
      atomicAdd(&ssum[64 * p + o0 + i], s); atomicAdd(&ssq[64 * p + o0 + i], sq);
    }
  }
  __syncthreads();
  if (t < 128) { atomicAdd(&stats[128 + t], ssum[t]); atomicAdd(&stats[256 + t], ssq[t]); }
}

__global__ __launch_bounds__(256) void k_skip(const float* __restrict__ featsT,
                                              const uint32_t* __restrict__ sidx,
                                              const float* __restrict__ Ws,
                                              float* __restrict__ ys,
                                              float* __restrict__ stats) {
  __shared__ float fin[64 * 65];
  __shared__ float wssT[64 * 129];
  __shared__ uint32_t s_si[64];
  __shared__ float ssum[128], ssq[128];
  int blk = blockIdx.x, t = threadIdx.x;
  int b = blk >> 4, m0 = (blk & 15) * 64;
  if (t < 64) s_si[t] = sidx[b * Mn + m0 + t];
  if (t < 128) { ssum[t] = 0.f; ssq[t] = 0.f; }
  __syncthreads();
  for (int i = t; i < 64 * 64; i += 256) {
    int mm = i >> 6, c = i & 63;
    fin[mm * 65 + c] = featsT[((size_t)b * Nn + s_si[mm]) * 64 + c];
  }
  for (int i = t; i < 128 * 64; i += 256) {
    int oo = i >> 6, cc = i & 63;
    wssT[cc * 129 + oo] = Ws[(size_t)oo * 64 + cc];
  }
  __syncthreads();
  int o = t & 127, mh = t >> 7;
  float s = 0.f, sq = 0.f;
  for (int mm = mh * 32; mm < mh * 32 + 32; ++mm) {
    float acc = 0.f;
    for (int c = 0; c < 64; ++c) acc = fmaf(wssT[c * 129 + o], fin[mm * 65 + c], acc);
    ys[((size_t)(b * Mn + m0 + mm)) * 128 + o] = acc;
    s += acc; sq = fmaf(acc, acc, sq);
  }
  atomicAdd(&ssum[o], s); atomicAdd(&ssq[o], sq);
  __syncthreads();
  if (t < 128) { atomicAdd(&stats[384 + t], ssum[t]); atomicAdd(&stats[512 + t], ssq[t]); }
}

__global__ void k_fin1(float* stats, const float* g1, const float* b1,
                       const float* gs, const float* bs) {
  int t = threadIdx.x;
  if (t >= 128) return;
  float mu  = stats[128 + t] * (1.f / 262144.f);
  float var = stats[256 + t] * (1.f / 262144.f) - mu * mu;
  float a = g1[t] / sqrtf(var + 1e-5f);
  stats[768 + t] = a;
  stats[896 + t] = b1[t] - mu * a;
  float mus  = stats[384 + t] * (1.f / 8192.f);
  float vars = stats[512 + t] * (1.f / 8192.f) - mus * mus;
  float as = gs[t] / sqrtf(vars + 1e-5f);
  stats[1024 + t] = as;
  stats[1152 + t] = bs[t] - mus * as;
}

__global__ __launch_bounds__(256) void k_out(const float* __restrict__ coords,
                                             const float* __restrict__ featsT,
                                             const uint32_t* __restrict__ sidx,
                                             const uint32_t* __restrict__ gidx,
                                             const float* __restrict__ W0,
                                             const float* __restrict__ W1,
                                             const float* __restrict__ wts,
                                             const float* __restrict__ ys,
                                             const float* __restrict__ stats,
                                             float* __restrict__ out_feat) {
  __shared__ float smU[13400];
  __shared__ uint32_t s_gi[128];
  __shared__ float s_qc[12];
  __shared__ float sw[4 * 36];
  __shared__ float red[128 * 5];
  float* xs = smU;  float* w0sT = smU + 67 * XST;
  float* hs = smU;  float* w1sT = smU + 64 * XST;
  int blk = blockIdx.x, t = threadIdx.x;
  int b = blk >> 8, m0 = (blk & 255) << 2;
  build_x(coords, featsT, sidx, gidx, W0, b, m0, t, xs, w0sT, s_gi, s_qc);
  if (t < 128) sw[(t >> 5) * 36 + (t & 31)] = wts[((size_t)(b * Mn + m0)) * 32 + t];
  int o0 = (t & 15) * 4, k0 = (t >> 4) * 8;
  int m = k0 >> 5, nb0 = k0 & 31;  // query idx (== wave id), neighbor offset
  float acc[32];
  conv1_acc(xs, w0sT, o0, k0, acc);
  float4 a04 = *(const float4*)&stats[640 + o0];
  float4 c04 = *(const float4*)&stats[704 + o0];
  float a0v[4] = {a04.x, a04.y, a04.z, a04.w};
  float c0v[4] = {c04.x, c04.y, c04.z, c04.w};
  __syncthreads();
#pragma unroll
  for (int i = 0; i < 4; ++i) {
    float h[8];
#pragma unroll
    for (int j = 0; j < 8; ++j) h[j] = fmaxf(fmaf(a0v[i], acc[i * 8 + j], c0v[i]), 0.f);
    *(float4*)&hs[(o0 + i) * XST + k0]     = make_float4(h[0], h[1], h[2], h[3]);
    *(float4*)&hs[(o0 + i) * XST + k0 + 4] = make_float4(h[4], h[5], h[6], h[7]);
  }
  for (int p = 0; p < 2; ++p) {
    __syncthreads();
    for (int i = t; i < 64 * 64; i += 256) {
      int oo = i >> 6, cc = i & 63;
      w1sT[cc * WST + oo] = W1[(size_t)(64 * p + oo) * 64 + cc];
    }
    __syncthreads();
    float acc2[32];
    conv2_acc(hs, w1sT, o0, k0, acc2);
    float4 swa = *(const float4*)&sw[m * 36 + nb0];
    float4 swb = *(const float4*)&sw[m * 36 + nb0 + 4];
    float wv[8] = {swa.x, swa.y, swa.z, swa.w, swb.x, swb.y, swb.z, swb.w};
    float4 a14 = *(const float4*)&stats[768 + 64 * p + o0];
    float4 c14 = *(const float4*)&stats[896 + 64 * p + o0];
    float a1v[4] = {a14.x, a14.y, a14.z, a14.w};
    float c1v[4] = {c14.x, c14.y, c14.z, c14.w};
    float r4[4];
#pragma unroll
    for (int i = 0; i < 4; ++i) {
      float r = 0.f;
#pragma unroll
      for (int j = 0; j < 8; ++j) {
        float msg = fmaxf(fmaf(a1v[i], acc2[i * 8 + j], c1v[i]), 0.f);
        r = fmaf(msg, wv[j], r);
      }
      r4[i] = r;
    }
#pragma unroll
    for (int i = 0; i < 4; ++i) {  // sum the 4 neighbor-subgroups (lane strides 16,32)
      float r = r4[i];
      r += __shfl_xor(r, 16, 64);
      r += __shfl_xor(r, 32, 64);
      r4[i] = r;
    }
    if ((t & 63) < 16) {
      float4 ysv = *(const float4*)&ys[((size_t)(b * Mn + m0 + m)) * 128 + 64 * p + o0];
      float4 as4 = *(const float4*)&stats[1024 + 64 * p + o0];
      float4 cs4 = *(const float4*)&stats[1152 + 64 * p + o0];
      float yv[4] = {ysv.x, ysv.y, ysv.z, ysv.w};
      float av[4] = {as4.x, as4.y, as4.z, as4.w};
      float cv[4] = {cs4.x, cs4.y, cs4.z, cs4.w};
#pragma unroll
      for (int i = 0; i < 4; ++i)
        red[(64 * p + o0 + i) * 5 + m] = fmaxf(r4[i] + fmaf(av[i], yv[i], cv[i]), 0.f);
    }
  }
  __syncthreads();
  for (int e = t; e < 512; e += 256) {
    int oo = e >> 2, mm = e & 3;
    out_feat[(size_t)b * 131072 + (size_t)oo * 1024 + m0 + mm] = red[oo * 5 + mm];
  }
}

// ---------------------------------------------------------------------------
extern "C" void kernel_launch(void* const* d_in, const int* in_sizes, int n_in,
                              void* d_out, int out_size, void* d_ws, size_t ws_size,
                              hipStream_t stream) {
  const float* coords = (const float*)d_in[0];
  const float* feats  = (const float*)d_in[1];
  const float* W0 = (const float*)d_in[2];
  const float* g0 = (const float*)d_in[3];
  const float* b0 = (const float*)d_in[4];
  const float* W1 = (const float*)d_in[5];
  const float* g1 = (const float*)d_in[6];
  const float* b1 = (const float*)d_in[7];
  const float* Ws = (const float*)d_in[8];
  const float* gs = (const float*)d_in[9];
  const float* bs = (const float*)d_in[10];

  float* out_coords = (float*)d_out;
  float* out_feat   = out_coords + (size_t)Bn * Mn * 3;

  char* w = (char*)d_ws;
  float*    featsT = (float*)w;    w += (size_t)Bn * Nn * CIN * 4;   // 8 MB
  uint32_t* sidx   = (uint32_t*)w; w += (size_t)Bn * Mn * 4;
  uint32_t* gidx   = (uint32_t*)w; w += (size_t)Bn * Mn * Kn * 4;
  float*    wts    = (float*)w;    w += (size_t)Bn * Mn * Kn * 4;
  float*    ys     = (float*)w;    w += (size_t)Bn * Mn * COUT * 4;  // 4 MB
  float*    stats  = (float*)w;    w += 1280 * 4;
  unsigned long long* gpart = (unsigned long long*)w; w += 8 * 128 * 8;  // 8 KB

  hipMemsetAsync(stats, 0, 640 * 4, stream);
  hipMemsetAsync(gpart, 0xFF, 8 * 128 * 8, stream);  // tags -> 2047, never a valid p
  hipLaunchKernelGGL(k_tr, dim3(512), dim3(256), 0, stream, feats, featsT);
  {
    void* args[] = {(void*)&coords, (void*)&sidx, (void*)&out_coords, (void*)&gpart};
    hipLaunchCooperativeKernel((void*)k_fps, dim3(128), dim3(256), args, 0, stream);
  }
  hipLaunchKernelGGL(k_knn,   dim3(8192), dim3(256), 0, stream, coords, sidx, gidx, wts);
  hipLaunchKernelGGL(k_conv1, dim3(2048), dim3(256), 0, stream, coords, featsT, sidx, gidx, W0, stats);
  hipLaunchKernelGGL(k_skip,  dim3(128),  dim3(256), 0, stream, featsT, sidx, Ws, ys, stats);
  hipLaunchKernelGGL(k_fin0,  dim3(1),    dim3(64),  0, stream, stats, g0, b0);
  hipLaunchKernelGGL(k_conv2, dim3(2048), dim3(256), 0, stream, coords, featsT, sidx, gidx, W0, W1, stats);
  hipLaunchKernelGGL(k_fin1,  dim3(1),    dim3(128), 0, stream, stats, g1, b1, gs, bs);
  hipLaunchKernelGGL(k_out,   dim3(2048), dim3(256), 0, stream, coords, featsT, sidx, gidx, W0, W1, wts, ys, stats, out_feat);
}

// Round 6
// 1219.312 us; speedup vs baseline: 3.3513x; 3.3513x over previous
//
#include <hip/hip_runtime.h>
#include <hip/hip_bf16.h>
#include <cstdint>

#define DEV __device__ __forceinline__

// Problem constants (from setup_inputs)
constexpr int Bn   = 8;
constexpr int Nn   = 4096;
constexpr int Mn   = 1024;   // N / STRIDE
constexpr int Kn   = 32;     // NSAMPLE
constexpr int CIN  = 64;
constexpr int COUT = 128;

// ---------------------------------------------------------------------------
// feats (B, 64, 4096) -> featsT (B, 4096, 64)
// ---------------------------------------------------------------------------
__global__ __launch_bounds__(256) void k_tr(const float* __restrict__ feats,
                                            float* __restrict__ featsT) {
  __shared__ float tile[64][65];
  int b = blockIdx.x >> 6, n0 = (blockIdx.x & 63) * 64;
  int t = threadIdx.x;
  int lane = t & 63, grp = t >> 6;
  for (int r = 0; r < 16; ++r) {
    int c = grp + r * 4;
    tile[c][lane] = feats[((size_t)b * 64 + c) * 4096 + n0 + lane];
  }
  __syncthreads();
  for (int r = 0; r < 16; ++r) {
    int n = grp + r * 4;
    featsT[((size_t)b * 4096 + n0 + n) * 64 + lane] = tile[lane][n];
  }
}

// ---------------------------------------------------------------------------
// FPS v4: 1 block/batch, 512 threads (8 waves, 2/SIMD), 8 CONTIGUOUS points
// per thread (lane order == index order). Wave reduce = tree8 -> f32 DPP max
// -> readlane + ballot + ffs (min-index tie-break, exact). Cross-wave merge =
// 8 u64 slots in LDS, 3-step DPP row max. One barrier/iter, double-buffered.
// Decision arithmetic bit-identical to numpy ref (no FMA contraction,
// first-index tie-break).
// ---------------------------------------------------------------------------
DEV float wave_max_f32(float x) {
#if __has_builtin(__builtin_amdgcn_update_dpp)
#define FSTEP(CTRL, RMASK)                                                      \
  {                                                                             \
    int o = __builtin_amdgcn_update_dpp(0, __float_as_int(x), CTRL, RMASK, 0xf, \
                                        false);                                 \
    x = fmaxf(x, __int_as_float(o));                                            \
  }
  FSTEP(0x111, 0xf)  // row_shr:1
  FSTEP(0x112, 0xf)  // row_shr:2
  FSTEP(0x114, 0xf)  // row_shr:4
  FSTEP(0x118, 0xf)  // row_shr:8
  FSTEP(0x142, 0xa)  // row_bcast:15 rows 1,3
  FSTEP(0x143, 0xc)  // row_bcast:31 rows 2,3
#undef FSTEP
#else
  for (int off = 1; off < 64; off <<= 1) x = fmaxf(x, __shfl_xor(x, off, 64));
#endif
  return x;  // lane 63 holds the wave max (all lanes in fallback)
}

DEV unsigned long long grp8_max_u64(unsigned long long k) {
#if __has_builtin(__builtin_amdgcn_update_dpp)
#define USTEP(CTRL)                                                                    \
  {                                                                                    \
    unsigned int lo = (unsigned int)__builtin_amdgcn_update_dpp(                       \
        0, (int)(unsigned int)k, CTRL, 0xf, 0xf, false);                               \
    unsigned int hi = (unsigned int)__builtin_amdgcn_update_dpp(                       \
        0, (int)(unsigned int)(k >> 32), CTRL, 0xf, 0xf, false);                       \
    unsigned long long o = ((unsigned long long)hi << 32) | lo;                        \
    if (o > k) k = o;                                                                  \
  }
  USTEP(0x111)  // row_shr:1
  USTEP(0x112)  // row_shr:2
  USTEP(0x114)  // row_shr:4
#undef USTEP
#else
  for (int off = 1; off < 8; off <<= 1) {
    unsigned int lo = __shfl_xor((unsigned int)k, off, 64);
    unsigned int hi = __shfl_xor((unsigned int)(k >> 32), off, 64);
    unsigned long long o = ((unsigned long long)hi << 32) | lo;
    if (o > k) k = o;
  }
#endif
  return k;  // lane 7 (of each 16-lane row) holds max of lanes 0..7 of that row
}

// One argmax round: local tree8 -> f32 DPP wave max -> ballot tie-break ->
// publish u64 (valbits<<12 | 4095-idx) -> barrier -> 8-slot DPP merge.
DEV uint32_t fps_round8(const float v[8], int t, unsigned long long (*part)[8], int p) {
  float v4[4]; int j4[4];
#pragma unroll
  for (int i = 0; i < 4; ++i) {
    bool r = v[2 * i + 1] > v[2 * i];
    v4[i] = r ? v[2 * i + 1] : v[2 * i];
    j4[i] = r ? 2 * i + 1 : 2 * i;
  }
  float v2[2]; int j2[2];
#pragma unroll
  for (int i = 0; i < 2; ++i) {
    bool r = v4[2 * i + 1] > v4[2 * i];
    v2[i] = r ? v4[2 * i + 1] : v4[2 * i];
    j2[i] = r ? j4[2 * i + 1] : j4[2 * i];
  }
  bool rr = v2[1] > v2[0];
  float bv = rr ? v2[1] : v2[0];
  int bj = rr ? j2[1] : j2[0];

  float wl = wave_max_f32(bv);
  float wmax = __int_as_float(__builtin_amdgcn_readlane(__float_as_int(wl), 63));
  unsigned long long mask = __ballot(bv == wmax);
  int Ls = (int)__ffsll(mask) - 1;           // lowest lane with the max
  int bjw = __shfl(bj, Ls, 64);              // its local index (Ls uniform)
  uint32_t idx = 8u * (uint32_t)((t & ~63) + Ls) + (uint32_t)bjw;
  const int sl = p & 1;
  if ((t & 63) == 0)
    part[sl][t >> 6] = ((unsigned long long)__float_as_uint(wmax) << 12) |
                       (unsigned long long)(4095u - idx);
  __syncthreads();
  unsigned long long kk = part[sl][t & 7];
  kk = grp8_max_u64(kk);
  unsigned int lo = (unsigned int)__builtin_amdgcn_readlane((int)(unsigned int)kk, 7);
  return 4095u - (lo & 4095u);
}

__global__ __launch_bounds__(512, 1) void k_fps(const float* __restrict__ coords,
                                                uint32_t* __restrict__ sidx,
                                                float* __restrict__ outc) {
  const int b = blockIdx.x, t = threadIdx.x;
  __shared__ float4 sp[Nn];                     // 64 KB
  __shared__ unsigned long long part[2][8];
  __shared__ uint32_t farl[Mn];
  __shared__ float s_mean[4];

  const float* cb = coords + (size_t)b * Nn * 3;
  for (int i = t; i < Nn; i += 512)
    sp[i] = make_float4(cb[3 * i], cb[3 * i + 1], cb[3 * i + 2], 0.f);
  __syncthreads();
  if (t == 0) {  // sequential in-order fp32 mean (numpy reduce order; proven)
    float ax = 0.f, ay = 0.f, az = 0.f;
    for (int i = 0; i < Nn; ++i) {
      float4 c = sp[i];
      ax = __fadd_rn(ax, c.x); ay = __fadd_rn(ay, c.y); az = __fadd_rn(az, c.z);
    }
    s_mean[0] = __fdiv_rn(ax, 4096.f);
    s_mean[1] = __fdiv_rn(ay, 4096.f);
    s_mean[2] = __fdiv_rn(az, 4096.f);
  }
  __syncthreads();

  float px[8], py[8], pz[8], md[8];
#pragma unroll
  for (int j = 0; j < 8; ++j) {
    float4 c = sp[8 * t + j];                   // contiguous per thread
    px[j] = c.x; py[j] = c.y; pz[j] = c.z;
    md[j] = __builtin_inff();
  }

  uint32_t far;
  {
    float mx = s_mean[0], my = s_mean[1], mz = s_mean[2];
    float tv[8];
#pragma unroll
    for (int j = 0; j < 8; ++j) {
      float dx = __fsub_rn(px[j], mx), dy = __fsub_rn(py[j], my), dz = __fsub_rn(pz[j], mz);
      tv[j] = __fadd_rn(__fadd_rn(__fmul_rn(dx, dx), __fmul_rn(dy, dy)), __fmul_rn(dz, dz));
    }
    far = fps_round8(tv, t, part, 0);
  }

  for (int p = 1; p < Mn; ++p) {
    if (t == 0) farl[p - 1] = far;
    float4 c = sp[far];
#pragma unroll
    for (int j = 0; j < 8; ++j) {
      float dx = __fsub_rn(px[j], c.x), dy = __fsub_rn(py[j], c.y), dz = __fsub_rn(pz[j], c.z);
      float d = __fadd_rn(__fadd_rn(__fmul_rn(dx, dx), __fmul_rn(dy, dy)), __fmul_rn(dz, dz));
      md[j] = fminf(md[j], d);
    }
    far = fps_round8(md, t, part, p);
  }
  if (t == 0) farl[Mn - 1] = far;
  __syncthreads();

  for (int i = t; i < Mn; i += 512) {
    uint32_t f = farl[i];
    sidx[b * Mn + i] = f;
    float4 c = sp[f];
    outc[(size_t)(b * Mn + i) * 3 + 0] = c.x;
    outc[(size_t)(b * Mn + i) * 3 + 1] = c.y;
    outc[(size_t)(b * Mn + i) * 3 + 2] = c.z;
  }
}

// ---------------------------------------------------------------------------
// 32-NN per query (== reference ball_query+knn fallback) + density weights.
// Compact within-radius candidates, rank-select 32 smallest (d2,idx) keys.
// Radius expansion 0.04 -> 0.16 -> inf if fewer than 32 candidates.
// ---------------------------------------------------------------------------
__global__ __launch_bounds__(256) void k_knn(const float* __restrict__ coords,
                                             const uint32_t* __restrict__ sidx,
                                             uint32_t* __restrict__ gidx,
                                             float* __restrict__ wts) {
  const int q = blockIdx.x;
  const int b = q >> 10;
  const int t = threadIdx.x;
  __shared__ unsigned long long keys[Nn + 2];
  __shared__ int s_cnt;
  __shared__ float s_q[4];
  __shared__ uint32_t s_sel[32];
  __shared__ float gx[32], gy[32], gz[32], g2[32];
  __shared__ float dmat[32 * 33];
  __shared__ float kth[32];
  __shared__ float s_raw[32];
  __shared__ float s_sum;

  if (t == 0) {
    uint32_t si = sidx[q];
    const float* c = &coords[((size_t)b * Nn + si) * 3];
    s_q[0] = c[0]; s_q[1] = c[1]; s_q[2] = c[2];
  }
  __syncthreads();
  float qx = s_q[0], qy = s_q[1], qz = s_q[2];
  float q2 = __fadd_rn(__fadd_rn(__fmul_rn(qx, qx), __fmul_rn(qy, qy)), __fmul_rn(qz, qz));
  const float* cb = coords + (size_t)b * Nn * 3;

  float thr = 0.04f;
  int cnt = 0;
  while (true) {
    if (t == 0) s_cnt = 0;
    __syncthreads();
    for (int j = 0; j < 16; ++j) {
      int i = t + 256 * j;
      float cx = cb[3 * i], cy = cb[3 * i + 1], cz = cb[3 * i + 2];
      float c2  = __fadd_rn(__fadd_rn(__fmul_rn(cx, cx), __fmul_rn(cy, cy)), __fmul_rn(cz, cz));
      float dot = __fadd_rn(__fadd_rn(__fmul_rn(qx, cx), __fmul_rn(qy, cy)), __fmul_rn(qz, cz));
      float d2  = __fsub_rn(__fadd_rn(q2, c2), __fmul_rn(2.f, dot));
      float d2c = fmaxf(d2, 1e-12f);
      bool pred = (d2c <= thr);
      unsigned long long mk = __ballot(pred);
      int base = 0;
      if ((t & 63) == 0 && mk) base = atomicAdd(&s_cnt, (int)__popcll(mk));
      base = __shfl(base, 0, 64);
      if (pred) {
        int pos = base + (int)__popcll(mk & ((1ull << (t & 63)) - 1ull));
        keys[pos] = ((unsigned long long)__float_as_uint(d2c) << 32) | (uint32_t)i;
      }
    }
    __syncthreads();
    cnt = s_cnt;
    if (cnt >= 32 || thr > 1.f) break;
    thr = (thr < 0.1f) ? 0.16f : 8.f;
    __syncthreads();
  }
  if (t == 0) { keys[cnt] = ~0ull; keys[cnt + 1] = ~0ull; }
  __syncthreads();
  int cnt2 = (cnt + 1) & ~1;
  for (int i = t; i < cnt; i += 256) {
    unsigned long long ki = keys[i];
    int r = 0;
    for (int j2 = 0; j2 < cnt2; j2 += 2) {
      unsigned long long a = keys[j2], c2 = keys[j2 + 1];
      r += (a < ki) + (c2 < ki);
    }
    if (r < 32) s_sel[r] = (uint32_t)ki;
  }
  __syncthreads();

  if (t < 32) {
    uint32_t gi = s_sel[t];
    gidx[(size_t)q * 32 + t] = gi;
    const float* c = &coords[((size_t)b * Nn + gi) * 3];
    float x = c[0], y = c[1], z = c[2];
    gx[t] = x; gy[t] = y; gz[t] = z;
    g2[t] = __fadd_rn(__fadd_rn(__fmul_rn(x, x), __fmul_rn(y, y)), __fmul_rn(z, z));
  }
  __syncthreads();
  for (int p = t; p < 1024; p += 256) {
    int i = p >> 5, jj = p & 31;
    float dot = __fadd_rn(__fadd_rn(__fmul_rn(gx[i], gx[jj]), __fmul_rn(gy[i], gy[jj])),
                          __fmul_rn(gz[i], gz[jj]));
    float d2 = __fsub_rn(__fadd_rn(g2[i], g2[jj]), __fmul_rn(2.f, dot));
    float dd = sqrtf(fmaxf(d2, 1e-12f));
    if (i == jj) dd = __builtin_inff();
    dmat[i * 33 + jj] = dd;
  }
  __syncthreads();
  for (int p = t; p < 1024; p += 256) {
    int i = p >> 5, jj = p & 31;
    float v = dmat[i * 33 + jj];
    int r = 0;
    for (int c = 0; c < 32; ++c) {
      float u = dmat[i * 33 + c];
      r += (u < v) || (u == v && c < jj);
    }
    if (r == 15) kth[i] = v;
  }
  __syncthreads();
  if (t < 32) { float x = fmaxf(kth[t], 1e-8f); s_raw[t] = x * x * x; }
  __syncthreads();
  if (t == 0) {
    float s = 0.f;
    for (int i2 = 0; i2 < 32; ++i2) s += s_raw[i2];
    s_sum = fmaxf(s, 1e-8f);
  }
  __syncthreads();
  if (t < 32) wts[(size_t)q * 32 + t] = s_raw[t] / s_sum;
}

// ---------------------------------------------------------------------------
// Conv pipeline. Tile = 4 queries x 32 neighbors (GEMM k-dim = 128).
// Thread tile: 4 outputs x 8 k (o0 = (t&15)*4, k0 = (t>>4)*8).
// LDS: xs[67][132] (row 0..2 = rel, 3..66 = feats), w0sT[67][68] (W0^T).
// ---------------------------------------------------------------------------
constexpr int XST = 132;
constexpr int WST = 68;

DEV void build_x(const float* __restrict__ coords, const float* __restrict__ featsT,
                 const uint32_t* __restrict__ sidx, const uint32_t* __restrict__ gidx,
                 const float* __restrict__ W0, int b, int m0, int t,
                 float* xs, float* w0sT, uint32_t* s_gi, float* s_qc) {
  for (int i = t; i < 64 * 67; i += 256) {
    int o = i / 67, c = i - o * 67;
    w0sT[c * WST + o] = W0[i];
  }
  if (t < 128) {
    s_gi[t] = gidx[((size_t)(b * Mn + m0)) * 32 + t];
  } else if (t < 132) {
    int mm = t - 128;
    uint32_t si = sidx[b * Mn + m0 + mm];
    const float* c = &coords[((size_t)b * Nn + si) * 3];
    s_qc[mm * 3 + 0] = c[0]; s_qc[mm * 3 + 1] = c[1]; s_qc[mm * 3 + 2] = c[2];
  }
  __syncthreads();
  if (t < 128) {
    int mm = t >> 5;
    const float* c = &coords[((size_t)b * Nn + s_gi[t]) * 3];
    xs[0 * XST + t] = (c[0] - s_qc[mm * 3 + 0]) / 0.2f;
    xs[1 * XST + t] = (c[1] - s_qc[mm * 3 + 1]) / 0.2f;
    xs[2 * XST + t] = (c[2] - s_qc[mm * 3 + 2]) / 0.2f;
  }
  {
    int c = t & 63, k0g = t >> 6;
    for (int r2 = 0; r2 < 32; ++r2) {
      int kk = k0g + 4 * r2;
      xs[(size_t)(3 + c) * XST + kk] = featsT[((size_t)b * Nn + s_gi[kk]) * 64 + c];
    }
  }
  __syncthreads();
}

DEV void conv1_acc(const float* xs, const float* w0sT, int o0, int k0, float acc[32]) {
#pragma unroll
  for (int i = 0; i < 32; ++i) acc[i] = 0.f;
  for (int c = 0; c < 67; ++c) {
    float4 w  = *(const float4*)&w0sT[c * WST + o0];
    float4 xa = *(const float4*)&xs[c * XST + k0];
    float4 xb = *(const float4*)&xs[c * XST + k0 + 4];
    float wv[4] = {w.x, w.y, w.z, w.w};
    float xv[8] = {xa.x, xa.y, xa.z, xa.w, xb.x, xb.y, xb.z, xb.w};
#pragma unroll
    for (int i = 0; i < 4; ++i)
#pragma unroll
      for (int j = 0; j < 8; ++j)
        acc[i * 8 + j] = fmaf(wv[i], xv[j], acc[i * 8 + j]);
  }
}

DEV void conv2_acc(const float* hs, const float* w1sT, int o0, int k0, float acc2[32]) {
#pragma unroll
  for (int i = 0; i < 32; ++i) acc2[i] = 0.f;
  for (int c = 0; c < 64; ++c) {
    float4 w  = *(const float4*)&w1sT[c * WST + o0];
    float4 xa = *(const float4*)&hs[c * XST + k0];
    float4 xb = *(const float4*)&hs[c * XST + k0 + 4];
    float wv[4] = {w.x, w.y, w.z, w.w};
    float xv[8] = {xa.x, xa.y, xa.z, xa.w, xb.x, xb.y, xb.z, xb.w};
#pragma unroll
    for (int i = 0; i < 4; ++i)
#pragma unroll
      for (int j = 0; j < 8; ++j)
        acc2[i * 8 + j] = fmaf(wv[i], xv[j], acc2[i * 8 + j]);
  }
}

// stats layout (floats): [0,64) s0 | [64,128) q0 | [128,256) s1 | [256,384) q1
// | [384,512) ss | [512,640) qs | 640 a0 | 704 c0 | 768 a1 | 896 c1
// | 1024 as | 1152 cs
__global__ __launch_bounds__(256) void k_conv1(const float* __restrict__ coords,
                                               const float* __restrict__ featsT,
                                               const uint32_t* __restrict__ sidx,
                                               const uint32_t* __restrict__ gidx,
                                               const float* __restrict__ W0,
                                               float* __restrict__ stats) {
  __shared__ float xs[67 * XST];
  __shared__ float w0sT[67 * WST];
  __shared__ uint32_t s_gi[128];
  __shared__ float s_qc[12];
  __shared__ float ssum[64], ssq[64];
  int blk = blockIdx.x, t = threadIdx.x;
  int b = blk >> 8, m0 = (blk & 255) << 2;
  if (t < 64) { ssum[t] = 0.f; ssq[t] = 0.f; }
  build_x(coords, featsT, sidx, gidx, W0, b, m0, t, xs, w0sT, s_gi, s_qc);
  int o0 = (t & 15) * 4, k0 = (t >> 4) * 8;
  float acc[32];
  conv1_acc(xs, w0sT, o0, k0, acc);
#pragma unroll
  for (int i = 0; i < 4; ++i) {
    float s = 0.f, sq = 0.f;
#pragma unroll
    for (int j = 0; j < 8; ++j) { s += acc[i * 8 + j]; sq = fmaf(acc[i * 8 + j], acc[i * 8 + j], sq); }
    atomicAdd(&ssum[o0 + i], s); atomicAdd(&ssq[o0 + i], sq);
  }
  __syncthreads();
  if (t < 64) { atomicAdd(&stats[t], ssum[t]); atomicAdd(&stats[64 + t], ssq[t]); }
}

__global__ void k_fin0(float* stats, const float* g0, const float* b0) {
  int t = threadIdx.x;
  if (t >= 64) return;
  float mu  = stats[t] * (1.f / 262144.f);
  float var = stats[64 + t] * (1.f / 262144.f) - mu * mu;
  float a = g0[t] / sqrtf(var + 1e-5f);
  stats[640 + t] = a;
  stats[704 + t] = b0[t] - mu * a;
}

__global__ __launch_bounds__(256) void k_conv2(const float* __restrict__ coords,
                                               const float* __restrict__ featsT,
                                               const uint32_t* __restrict__ sidx,
                                               const uint32_t* __restrict__ gidx,
                                               const float* __restrict__ W0,
                                               const float* __restrict__ W1,
                                               float* __restrict__ stats) {
  __shared__ float smU[13400];  // xs+w0sT (8844+4556) | hs+w1sT (8448+4352)
  __shared__ uint32_t s_gi[128];
  __shared__ float s_qc[12];
  __shared__ float ssum[128], ssq[128];
  float* xs = smU;  float* w0sT = smU + 67 * XST;
  float* hs = smU;  float* w1sT = smU + 64 * XST;
  int blk = blockIdx.x, t = threadIdx.x;
  int b = blk >> 8, m0 = (blk & 255) << 2;
  if (t < 128) { ssum[t] = 0.f; ssq[t] = 0.f; }
  build_x(coords, featsT, sidx, gidx, W0, b, m0, t, xs, w0sT, s_gi, s_qc);
  int o0 = (t & 15) * 4, k0 = (t >> 4) * 8;
  float acc[32];
  conv1_acc(xs, w0sT, o0, k0, acc);
  float4 a04 = *(const float4*)&stats[640 + o0];
  float4 c04 = *(const float4*)&stats[704 + o0];
  float a0v[4] = {a04.x, a04.y, a04.z, a04.w};
  float c0v[4] = {c04.x, c04.y, c04.z, c04.w};
  __syncthreads();  // all conv1 LDS reads complete; smU repurposed
#pragma unroll
  for (int i = 0; i < 4; ++i) {
    float h[8];
#pragma unroll
    for (int j = 0; j < 8; ++j) h[j] = fmaxf(fmaf(a0v[i], acc[i * 8 + j], c0v[i]), 0.f);
    *(float4*)&hs[(o0 + i) * XST + k0]     = make_float4(h[0], h[1], h[2], h[3]);
    *(float4*)&hs[(o0 + i) * XST + k0 + 4] = make_float4(h[4], h[5], h[6], h[7]);
  }
  for (int p = 0; p < 2; ++p) {
    __syncthreads();
    for (int i = t; i < 64 * 64; i += 256) {
      int oo = i >> 6, cc = i & 63;
      w1sT[cc * WST + oo] = W1[(size_t)(64 * p + oo) * 64 + cc];
    }
    __syncthreads();
    float acc2[32];
    conv2_acc(hs, w1sT, o0, k0, acc2);
#pragma unroll
    for (int i = 0; i < 4; ++i) {
      float s = 0.f, sq = 0.f;
#pragma unroll
      for (int j = 0; j < 8; ++j) { s += acc2[i * 8 + j]; sq = fmaf(acc2[i * 8 + j], acc2[i * 8 + j], sq); }
      atomicAdd(&ssum[64 * p + o0 + i], s); atomicAdd(&ssq[64 * p + o0 + i], sq);
    }
  }
  __syncthreads();
  if (t < 128) { atomicAdd(&stats[128 + t], ssum[t]); atomicAdd(&stats[256 + t], ssq[t]); }
}

__global__ __launch_bounds__(256) void k_skip(const float* __restrict__ featsT,
                                              const uint32_t* __restrict__ sidx,
                                              const float* __restrict__ Ws,
                                              float* __restrict__ ys,
                                              float* __restrict__ stats) {
  __shared__ float fin[64 * 65];
  __shared__ float wssT[64 * 129];
  __shared__ uint32_t s_si[64];
  __shared__ float ssum[128], ssq[128];
  int blk = blockIdx.x, t = threadIdx.x;
  int b = blk >> 4, m0 = (blk & 15) * 64;
  if (t < 64) s_si[t] = sidx[b * Mn + m0 + t];
  if (t < 128) { ssum[t] = 0.f; ssq[t] = 0.f; }
  __syncthreads();
  for (int i = t; i < 64 * 64; i += 256) {
    int mm = i >> 6, c = i & 63;
    fin[mm * 65 + c] = featsT[((size_t)b * Nn + s_si[mm]) * 64 + c];
  }
  for (int i = t; i < 128 * 64; i += 256) {
    int oo = i >> 6, cc = i & 63;
    wssT[cc * 129 + oo] = Ws[(size_t)oo * 64 + cc];
  }
  __syncthreads();
  int o = t & 127, mh = t >> 7;
  float s = 0.f, sq = 0.f;
  for (int mm = mh * 32; mm < mh * 32 + 32; ++mm) {
    float acc = 0.f;
    for (int c = 0; c < 64; ++c) acc = fmaf(wssT[c * 129 + o], fin[mm * 65 + c], acc);
    ys[((size_t)(b * Mn + m0 + mm)) * 128 + o] = acc;
    s += acc; sq = fmaf(acc, acc, sq);
  }
  atomicAdd(&ssum[o], s); atomicAdd(&ssq[o], sq);
  __syncthreads();
  if (t < 128) { atomicAdd(&stats[384 + t], ssum[t]); atomicAdd(&stats[512 + t], ssq[t]); }
}

__global__ void k_fin1(float* stats, const float* g1, const float* b1,
                       const float* gs, const float* bs) {
  int t = threadIdx.x;
  if (t >= 128) return;
  float mu  = stats[128 + t] * (1.f / 262144.f);
  float var = stats[256 + t] * (1.f / 262144.f) - mu * mu;
  float a = g1[t] / sqrtf(var + 1e-5f);
  stats[768 + t] = a;
  stats[896 + t] = b1[t] - mu * a;
  float mus  = stats[384 + t] * (1.f / 8192.f);
  float vars = stats[512 + t] * (1.f / 8192.f) - mus * mus;
  float as = gs[t] / sqrtf(vars + 1e-5f);
  stats[1024 + t] = as;
  stats[1152 + t] = bs[t] - mus * as;
}

__global__ __launch_bounds__(256) void k_out(const float* __restrict__ coords,
                                             const float* __restrict__ featsT,
                                             const uint32_t* __restrict__ sidx,
                                             const uint32_t* __restrict__ gidx,
                                             const float* __restrict__ W0,
                                             const float* __restrict__ W1,
                                             const float* __restrict__ wts,
                                             const float* __restrict__ ys,
                                             const float* __restrict__ stats,
                                             float* __restrict__ out_feat) {
  __shared__ float smU[13400];
  __shared__ uint32_t s_gi[128];
  __shared__ float s_qc[12];
  __shared__ float sw[4 * 36];
  __shared__ float red[128 * 5];
  float* xs = smU;  float* w0sT = smU + 67 * XST;
  float* hs = smU;  float* w1sT = smU + 64 * XST;
  int blk = blockIdx.x, t = threadIdx.x;
  int b = blk >> 8, m0 = (blk & 255) << 2;
  build_x(coords, featsT, sidx, gidx, W0, b, m0, t, xs, w0sT, s_gi, s_qc);
  if (t < 128) sw[(t >> 5) * 36 + (t & 31)] = wts[((size_t)(b * Mn + m0)) * 32 + t];
  int o0 = (t & 15) * 4, k0 = (t >> 4) * 8;
  int m = k0 >> 5, nb0 = k0 & 31;  // query idx (== wave id), neighbor offset
  float acc[32];
  conv1_acc(xs, w0sT, o0, k0, acc);
  float4 a04 = *(const float4*)&stats[640 + o0];
  float4 c04 = *(const float4*)&stats[704 + o0];
  float a0v[4] = {a04.x, a04.y, a04.z, a04.w};
  float c0v[4] = {c04.x, c04.y, c04.z, c04.w};
  __syncthreads();
#pragma unroll
  for (int i = 0; i < 4; ++i) {
    float h[8];
#pragma unroll
    for (int j = 0; j < 8; ++j) h[j] = fmaxf(fmaf(a0v[i], acc[i * 8 + j], c0v[i]), 0.f);
    *(float4*)&hs[(o0 + i) * XST + k0]     = make_float4(h[0], h[1], h[2], h[3]);
    *(float4*)&hs[(o0 + i) * XST + k0 + 4] = make_float4(h[4], h[5], h[6], h[7]);
  }
  for (int p = 0; p < 2; ++p) {
    __syncthreads();
    for (int i = t; i < 64 * 64; i += 256) {
      int oo = i >> 6, cc = i & 63;
      w1sT[cc * WST + oo] = W1[(size_t)(64 * p + oo) * 64 + cc];
    }
    __syncthreads();
    float acc2[32];
    conv2_acc(hs, w1sT, o0, k0, acc2);
    float4 swa = *(const float4*)&sw[m * 36 + nb0];
    float4 swb = *(const float4*)&sw[m * 36 + nb0 + 4];
    float wv[8] = {swa.x, swa.y, swa.z, swa.w, swb.x, swb.y, swb.z, swb.w};
    float4 a14 = *(const float4*)&stats[768 + 64 * p + o0];
    float4 c14 = *(const float4*)&stats[896 + 64 * p + o0];
    float a1v[4] = {a14.x, a14.y, a14.z, a14.w};
    float c1v[4] = {c14.x, c14.y, c14.z, c14.w};
    float r4[4];
#pragma unroll
    for (int i = 0; i < 4; ++i) {
      float r = 0.f;
#pragma unroll
      for (int j = 0; j < 8; ++j) {
        float msg = fmaxf(fmaf(a1v[i], acc2[i * 8 + j], c1v[i]), 0.f);
        r = fmaf(msg, wv[j], r);
      }
      r4[i] = r;
    }
#pragma unroll
    for (int i = 0; i < 4; ++i) {  // sum the 4 neighbor-subgroups (lane strides 16,32)
      float r = r4[i];
      r += __shfl_xor(r, 16, 64);
      r += __shfl_xor(r, 32, 64);
      r4[i] = r;
    }
    if ((t & 63) < 16) {
      float4 ysv = *(const float4*)&ys[((size_t)(b * Mn + m0 + m)) * 128 + 64 * p + o0];
      float4 as4 = *(const float4*)&stats[1024 + 64 * p + o0];
      float4 cs4 = *(const float4*)&stats[1152 + 64 * p + o0];
      float yv[4] = {ysv.x, ysv.y, ysv.z, ysv.w};
      float av[4] = {as4.x, as4.y, as4.z, as4.w};
      float cv[4] = {cs4.x, cs4.y, cs4.z, cs4.w};
#pragma unroll
      for (int i = 0; i < 4; ++i)
        red[(64 * p + o0 + i) * 5 + m] = fmaxf(r4[i] + fmaf(av[i], yv[i], cv[i]), 0.f);
    }
  }
  __syncthreads();
  for (int e = t; e < 512; e += 256) {
    int oo = e >> 2, mm = e & 3;
    out_feat[(size_t)b * 131072 + (size_t)oo * 1024 + m0 + mm] = red[oo * 5 + mm];
  }
}

// ---------------------------------------------------------------------------
extern "C" void kernel_launch(void* const* d_in, const int* in_sizes, int n_in,
                              void* d_out, int out_size, void* d_ws, size_t ws_size,
                              hipStream_t stream) {
  const float* coords = (const float*)d_in[0];
  const float* feats  = (const float*)d_in[1];
  const float* W0 = (const float*)d_in[2];
  const float* g0 = (const float*)d_in[3];
  const float* b0 = (const float*)d_in[4];
  const float* W1 = (const float*)d_in[5];
  const float* g1 = (const float*)d_in[6];
  const float* b1 = (const float*)d_in[7];
  const float* Ws = (const float*)d_in[8];
  const float* gs = (const float*)d_in[9];
  const float* bs = (const float*)d_in[10];

  float* out_coords = (float*)d_out;
  float* out_feat   = out_coords + (size_t)Bn * Mn * 3;

  char* w = (char*)d_ws;
  float*    featsT = (float*)w;    w += (size_t)Bn * Nn * CIN * 4;   // 8 MB
  uint32_t* sidx   = (uint32_t*)w; w += (size_t)Bn * Mn * 4;
  uint32_t* gidx   = (uint32_t*)w; w += (size_t)Bn * Mn * Kn * 4;
  float*    wts    = (float*)w;    w += (size_t)Bn * Mn * Kn * 4;
  float*    ys     = (float*)w;    w += (size_t)Bn * Mn * COUT * 4;  // 4 MB
  float*    stats  = (float*)w;    w += 1280 * 4;

  hipMemsetAsync(stats, 0, 640 * 4, stream);
  hipLaunchKernelGGL(k_tr,    dim3(512),  dim3(256), 0, stream, feats, featsT);
  hipLaunchKernelGGL(k_fps,   dim3(8),    dim3(512), 0, stream, coords, sidx, out_coords);
  hipLaunchKernelGGL(k_knn,   dim3(8192), dim3(256), 0, stream, coords, sidx, gidx, wts);
  hipLaunchKernelGGL(k_conv1, dim3(2048), dim3(256), 0, stream, coords, featsT, sidx, gidx, W0, stats);
  hipLaunchKernelGGL(k_skip,  dim3(128),  dim3(256), 0, stream, featsT, sidx, Ws, ys, stats);
  hipLaunchKernelGGL(k_fin0,  dim3(1),    dim3(64),  0, stream, stats, g0, b0);
  hipLaunchKernelGGL(k_conv2, dim3(2048), dim3(256), 0, stream, coords, featsT, sidx, gidx, W0, W1, stats);
  hipLaunchKernelGGL(k_fin1,  dim3(1),    dim3(128), 0, stream, stats, g1, b1, gs, bs);
  hipLaunchKernelGGL(k_out,   dim3(2048), dim3(256), 0, stream, coords, featsT, sidx, gidx, W0, W1, wts, ys, stats, out_feat);
}